// Round 7
// baseline (248.639 us; speedup 1.0000x reference)
//
#include <hip/hip_runtime.h>

// B=32, C=3, H=512, W=512 -> 96 flat images. ONE kernel, 3072 blocks:
//  per block = (img, 8x16-pooled tile). Small tile -> 25 KB LDS -> 6 blocks/CU
//  (r6 post-mortem: 47 KB tile => 3 blocks/CU => latency-bound at 62% VALUBusy).
//  phase 0: Haar DWT -> cA 38x70 f16 tile in LDS; owned 32x64 cH/cV -> d_out high.
//  conv1(1->16 fp32 VALU)+relu+pool -> h1 [18][34][16ic] f16 LDS.
//  conv2(16->8) MFMA f16 (K=32 = 2 taps x 16 ic, 5 steps, tap-9 slot zero-B).
//  pool in-lane + shfl_xor(16) -> h2 LDS (aliases cA), conv3(8->4,1x1) -> low.
// d_out = low (1,572,864 f32) ++ high (12,582,912 f32)

typedef _Float16 f16x8 __attribute__((ext_vector_type(8)));
typedef _Float16 f16x2 __attribute__((ext_vector_type(2)));
typedef float    f32x4 __attribute__((ext_vector_type(4)));

__global__ __launch_bounds__(256, 6) void fused_all_kernel(
    const float* __restrict__ x,
    const float* __restrict__ w1, const float* __restrict__ b1,
    const float* __restrict__ w2, const float* __restrict__ b2,
    const float* __restrict__ w3, const float* __restrict__ b3,
    float* __restrict__ outLow, float* __restrict__ outHigh)
{
    __shared__ __align__(16) float    smem0[1330];        // ca f16[38*70]=5320B; later h2b f32[1024]
    __shared__ __align__(16) _Float16 h1s[18 * 34 * 16];  // [row][col][16 ic], 19584 B

    _Float16* ca  = (_Float16*)smem0;
    float*    h2b = smem0;

    int img = blockIdx.x >> 5;
    int t   = blockIdx.x & 31;
    int ty = t >> 2, tx = t & 3;                // 8x4 tiles of 8x16 pooled outputs
    int hy0 = ty * 16 - 1, hx0 = tx * 32 - 1;   // h1 tile origin (18x34 incl halo)
    int cy0 = ty * 32 - 3, cx0 = tx * 64 - 3;   // cA tile origin (38x70)

    const float* xi = x + img * 262144;
    float* hb = outHigh + img * 131072;

    int lane = threadIdx.x & 63;
    int wid  = threadIdx.x >> 6;
    int q = lane >> 4, m = lane & 15;
    int ppy = m >> 2, ppx = m & 3;              // pixel within 4x4 M-tile
    int wy = wid >> 1, wx = wid & 1;            // wave region (8x16 pre-pool)

    // ---- Phase 0a: owned 32x64 cA (coalesced float4), cH/cV -> global ----
    #pragma unroll
    for (int k = 0; k < 2; ++k) {
        int i = threadIdx.x + k * 256;          // 512 tasks
        int row = i >> 4, cg = i & 15;
        int gy = ty * 32 + row;
        int gx = tx * 64 + cg * 4;
        const float* r0 = xi + (2 * gy) * 512 + 2 * gx;
        const float* r1 = r0 + 512;
        float4 t0 = *(const float4*)(r0);
        float4 t1 = *(const float4*)(r0 + 4);
        float4 u0 = *(const float4*)(r1);
        float4 u1 = *(const float4*)(r1 + 4);
        float4 vA, vH, vV;
        vA.x = (t0.x + t0.y + u0.x + u0.y) * 0.5f;
        vH.x = (t0.x + t0.y - u0.x - u0.y) * 0.5f;
        vV.x = (t0.x - t0.y + u0.x - u0.y) * 0.5f;
        vA.y = (t0.z + t0.w + u0.z + u0.w) * 0.5f;
        vH.y = (t0.z + t0.w - u0.z - u0.w) * 0.5f;
        vV.y = (t0.z - t0.w + u0.z - u0.w) * 0.5f;
        vA.z = (t1.x + t1.y + u1.x + u1.y) * 0.5f;
        vH.z = (t1.x + t1.y - u1.x - u1.y) * 0.5f;
        vV.z = (t1.x - t1.y + u1.x - u1.y) * 0.5f;
        vA.w = (t1.z + t1.w + u1.z + u1.w) * 0.5f;
        vH.w = (t1.z + t1.w - u1.z - u1.w) * 0.5f;
        vV.w = (t1.z - t1.w + u1.z - u1.w) * 0.5f;
        int po = (gy << 8) + gx;
        *(float4*)(hb + po) = vH;
        *(float4*)(hb + 65536 + po) = vV;
        _Float16* cp = ca + (row + 3) * 70 + cg * 4 + 3;
        cp[0] = (_Float16)vA.x; cp[1] = (_Float16)vA.y;
        cp[2] = (_Float16)vA.z; cp[3] = (_Float16)vA.w;
    }

    // ---- Phase 0b: 3-wide halo ring of cA (612 points), vA only ----
    // rows {0,1,2}, rows {35,36,37}, middle rows 3..34 x cols {0,1,2,67,68,69}
    #pragma unroll 1
    for (int k = 0; k < 3; ++k) {
        int i = threadIdx.x + k * 256;
        if (i < 612) {
            int r, c;
            if (i < 210)      { r = i / 70;              c = i - r * 70; }
            else if (i < 420) { int j = i - 210; int rr = j / 70; r = 35 + rr; c = j - rr * 70; }
            else              { int j = i - 420; r = 3 + j / 6; int k6 = j - (j / 6) * 6;
                                c = (k6 < 3) ? k6 : (64 + k6); }   // {0,1,2,67,68,69}
            int gy = cy0 + r, gx = cx0 + c;
            float v = 0.f;
            if ((unsigned)gy < 256u && (unsigned)gx < 256u) {
                const float* p0 = xi + (2 * gy) * 512 + 2 * gx;
                float2 a = *(const float2*)(p0);
                float2 b = *(const float2*)(p0 + 512);
                v = (a.x + a.y + b.x + b.y) * 0.5f;
            }
            ca[r * 70 + c] = (_Float16)v;
        }
    }

    __syncthreads();

    // ---- conv1 (1->16) + relu + pool2 -> h1s [18][34][16] f16 ----
    #pragma unroll 1
    for (int k = 0; k < 3; ++k) {
        int i = threadIdx.x + k * 256;          // 612 tasks
        if (i < 612) {
            int hy = i / 34, hx = i - hy * 34;
            const _Float16* pb = ca + (2 * hy) * 70 + 2 * hx;
            float patch[4][4];
            #pragma unroll
            for (int r = 0; r < 4; ++r) {
                f16x2 a = *(const f16x2*)(pb + r * 70);
                f16x2 b = *(const f16x2*)(pb + r * 70 + 2);
                patch[r][0] = (float)a.x; patch[r][1] = (float)a.y;
                patch[r][2] = (float)b.x; patch[r][3] = (float)b.y;
            }
            bool oob = ((unsigned)(hy0 + hy) >= 128u) | ((unsigned)(hx0 + hx) >= 128u);
            f16x8 ov0, ov1;
            #pragma unroll
            for (int oc = 0; oc < 16; ++oc) {
                float p00 = 0.f, p01 = 0.f, p10 = 0.f, p11 = 0.f;
                #pragma unroll
                for (int ky = 0; ky < 3; ++ky)
                    #pragma unroll
                    for (int kx = 0; kx < 3; ++kx) {
                        float wvv = w1[oc * 9 + ky * 3 + kx];   // uniform s_load
                        p00 += patch[ky][kx]         * wvv;
                        p01 += patch[ky][kx + 1]     * wvv;
                        p10 += patch[ky + 1][kx]     * wvv;
                        p11 += patch[ky + 1][kx + 1] * wvv;
                    }
                float mm = fmaxf(fmaxf(p00, p01), fmaxf(p10, p11)) + b1[oc];
                mm = fmaxf(mm, 0.f);
                _Float16 hv = (_Float16)(oob ? 0.f : mm);
                if (oc < 8) ov0[oc] = hv; else ov1[oc - 8] = hv;
            }
            *(f16x8*)(h1s + (hy * 34 + hx) * 16)     = ov0;
            *(f16x8*)(h1s + (hy * 34 + hx) * 16 + 8) = ov1;
        }
    }

    __syncthreads();
    // (ca dead; smem0 reused as h2b)

    // ---- B fragments: 5 K-steps, K=32 = 2 taps x 16 ic; tap tt = 2s + (q>>1) ----
    f16x8 Bf[5];
    #pragma unroll
    for (int s = 0; s < 5; ++s) {
        int tt = 2 * s + (q >> 1);
        f16x8 bf;
        #pragma unroll
        for (int j = 0; j < 8; ++j) {
            int ic = (q & 1) * 8 + j;
            float wvv = 0.f;
            if (m < 8 && tt < 9) wvv = w2[(m * 16 + ic) * 9 + tt];
            bf[j] = (_Float16)wvv;
        }
        Bf[s] = bf;
    }
    float bb2 = (m < 8) ? b2[m] : 0.f;

    int offA[5];
    #pragma unroll
    for (int s = 0; s < 5; ++s) {
        int tt = 2 * s + (q >> 1);
        int ttc = (tt > 8) ? 8 : tt;            // tap 9 -> valid addr, B=0
        int ky = ttc / 3, kx = ttc - 3 * ky;
        offA[s] = ((ppy + ky) * 34 + (ppx + kx)) * 16 + (q & 1) * 8;
    }

    // ---- conv2 MFMA per M-tile (8 per wave), pool, -> h2b ----
    #pragma unroll 2
    for (int mt = 0; mt < 8; ++mt) {
        int my = mt >> 2, mx = mt & 3;
        int pbase = ((wy * 8 + my * 4) * 34 + (wx * 16 + mx * 4)) * 16;
        f32x4 acc = (f32x4){0.f, 0.f, 0.f, 0.f};
        #pragma unroll
        for (int s = 0; s < 5; ++s) {
            f16x8 a = *(const f16x8*)(h1s + pbase + offA[s]);
            acc = __builtin_amdgcn_mfma_f32_16x16x32_f16(a, Bf[s], acc, 0, 0, 0);
        }
        // D: lane(q,m) reg r -> pixel (py=q, px=r), oc=m. Pool cols in-lane, rows xor16.
        float u0 = fmaxf(acc[0], acc[1]);
        float u1 = fmaxf(acc[2], acc[3]);
        float v0 = fmaxf(u0, __shfl_xor(u0, 16, 64));
        float v1 = fmaxf(u1, __shfl_xor(u1, 16, 64));
        float h20 = fmaxf(v0 + bb2, 0.f);
        float h21 = fmaxf(v1 + bb2, 0.f);
        if (m < 8 && (q & 1) == 0) {
            int Yp = wy * 4 + my * 2 + (q >> 1);
            int Xp = wx * 8 + mx * 2;
            h2b[(Yp * 16 + Xp) * 8 + m]     = h20;
            h2b[(Yp * 16 + Xp + 1) * 8 + m] = h21;
        }
    }
    __syncthreads();

    // ---- conv3 (1x1, 8->4) -> low ----
    if (threadIdx.x < 128) {
        int Yp = threadIdx.x >> 4, Xp = threadIdx.x & 15;
        const float* hv = h2b + (Yp * 16 + Xp) * 8;
        float4 va = *(const float4*)(hv);
        float4 vb = *(const float4*)(hv + 4);
        float h2v[8] = {va.x, va.y, va.z, va.w, vb.x, vb.y, vb.z, vb.w};
        float* dst = outLow + img * 16384;
        int pos = (ty * 8 + Yp) * 64 + tx * 16 + Xp;
        #pragma unroll
        for (int oc3 = 0; oc3 < 4; ++oc3) {
            float s = b3[oc3];
            #pragma unroll
            for (int ic = 0; ic < 8; ++ic) s += w3[oc3 * 8 + ic] * h2v[ic];
            dst[oc3 * 4096 + pos] = s;
        }
    }
}

extern "C" void kernel_launch(void* const* d_in, const int* in_sizes, int n_in,
                              void* d_out, int out_size, void* d_ws, size_t ws_size,
                              hipStream_t stream) {
    const float* x  = (const float*)d_in[0];
    const float* w1 = (const float*)d_in[1];
    const float* b1 = (const float*)d_in[2];
    const float* w2 = (const float*)d_in[3];
    const float* b2 = (const float*)d_in[4];
    const float* w3 = (const float*)d_in[5];
    const float* b3 = (const float*)d_in[6];
    float* out     = (float*)d_out;
    float* outLow  = out;                 // 1,572,864 floats
    float* outHigh = out + 1572864;       // 12,582,912 floats

    fused_all_kernel<<<3072, 256, 0, stream>>>(x, w1, b1, w2, b2, w3, b3,
                                               outLow, outHigh);
}